// Round 13
// baseline (127.865 us; speedup 1.0000x reference)
//
#include <hip/hip_runtime.h>
#include <stdint.h>

// hetero_effect_graph: 2-layer RGCN over dense level-partitioned bipartite graph.
// 5 dispatches:
//  k_init  : [bx<48] transpose+bf16 weights; [bx>=48] lev nibbles k-major, inv, xe->bf16
//  k_gemm  : m1 = relu(xm@root1+b1); z1[r] = pack(xm@W1[r])
//  k_convA : conv1 partial slabsA (4-wave 128x128, wave 64x64, levq hoisted, kk-stagger,
//            root1 on ks<8) + 80 fused blocks: z2[r] = pack(m1@W2[r])
//  k_convB : conv2-masked partial slabsB (same core, no root) + 79 fused red1 blocks:
//            e1 = relu(sum slabsA + b1) -> LDS; e1@root2 -> rootslab (f32)
//  k_red2  : out = sum slabsB + rootslab + b2 (f32)

#define NE 10000
#define NM 2048
#define NEPAD 10112   // 79 * 128
#define MB128 79      // NEPAD / 128
#define KSPLIT 16

typedef short bf8_t __attribute__((ext_vector_type(8)));
typedef float f16f  __attribute__((ext_vector_type(16)));

__device__ __forceinline__ uint16_t f2bf(float f){
  uint32_t u = __float_as_uint(f);
  u += 0x7FFFu + ((u >> 16) & 1u);
  return (uint16_t)(u >> 16);
}

__device__ __forceinline__ f16f mfma32(bf8_t a, bf8_t b, f16f c){
  return __builtin_amdgcn_mfma_f32_32x32x16_bf16(a, b, c, 0, 0, 0);
}

// ---- fused: weight prep (48 blocks) + lev/inv/xebf (316 blocks) ----
__global__ __launch_bounds__(256) void k_init(
    const float* __restrict__ root1, const float* __restrict__ root2,
    const float* __restrict__ W1, const float* __restrict__ W2,
    uint16_t* __restrict__ r1t, uint16_t* __restrict__ r2t,
    uint16_t* __restrict__ w1t, uint16_t* __restrict__ w2t,
    const float* __restrict__ w, const float* __restrict__ xe,
    uint32_t* __restrict__ levq, float* __restrict__ inv,
    uint16_t* __restrict__ xebf){
  int t = threadIdx.x;
  if (blockIdx.x < 48){               // ---- weight transpose+convert ----
    int idx = blockIdx.x*4096 + t;
    #pragma unroll
    for (int it = 0; it < 16; it++, idx += 256){
      int slab = idx >> 14;
      int pos  = idx & 16383;
      int d = pos >> 7, k = pos & 127;
      float v; uint16_t* dst;
      if (slab == 0)      { v = root1[k*128 + d]; dst = r1t; }
      else if (slab == 1) { v = root2[k*128 + d]; dst = r2t; }
      else if (slab < 7)  { v = W1[(slab-1)*16384 + k*128 + d]; dst = w1t + (slab-2)*16384; }
      else                { v = W2[(slab-6)*16384 + k*128 + d]; dst = w2t + (slab-7)*16384; }
      dst[pos] = f2bf(v);
    }
    return;
  }
  // ---- lev part: 32 rows per block ----
  int brow = (blockIdx.x - 48) * 32;
  int rloc = t >> 3, p = t & 7;          // 8 threads per row
  int row = brow + rloc;
  bool active = row < NE;
  const float* wr = w + (size_t)row * NM;
  unsigned long long cnt = 0ull;         // 5 x 12-bit packed relation counters
  __shared__ uint32_t tile[32][33];

  for (int cp = 0; cp < 8; cp++){        // 8 column-panels of 256 cols
    uint32_t packs[4];
    #pragma unroll
    for (int q = 0; q < 4; q++){
      int gck = cp*32 + p + 8*q;         // global 8-col chunk
      uint32_t L = 0;
      if (active){
        const float4* f = (const float4*)(wr + gck*8);
        float4 f0 = f[0], f1 = f[1];
        float wv[8] = {f0.x,f0.y,f0.z,f0.w, f1.x,f1.y,f1.z,f1.w};
        #pragma unroll
        for (int e = 0; e < 8; e++){
          int s = (int)ceilf(wv[e]*6.0f);          // lev+1 in 1..6
          if (s >= 2) cnt += 1ull << (12*(s-2));   // relations 1..5
          L |= (uint32_t)s << (4*e);
        }
      }
      packs[q] = L;
    }
    __syncthreads();
    #pragma unroll
    for (int q = 0; q < 4; q++) tile[p + 8*q][rloc] = packs[q];
    __syncthreads();
    int ckk = t >> 3;
    int r4  = (t & 7) * 4;
    size_t base = (size_t)(cp*32 + ckk) * NEPAD + brow + r4;
    *(uint4*)(levq + base) = make_uint4(tile[ckk][r4], tile[ckk][r4+1],
                                        tile[ckk][r4+2], tile[ckk][r4+3]);
  }

  unsigned long long c = cnt;
  c += __shfl_xor(c, 1);
  c += __shfl_xor(c, 2);
  c += __shfl_xor(c, 4);
  if (p == 0 && row < NEPAD){
    if (active){
      inv[row*8 + 0] = 0.f; inv[row*8 + 6] = 0.f; inv[row*8 + 7] = 0.f;
      #pragma unroll
      for (int r = 1; r <= 5; r++){
        uint32_t cc = (uint32_t)((c >> (12*(r-1))) & 0xFFFull);
        inv[row*8 + r] = cc ? 1.0f/(float)cc : 0.f;
      }
    } else {
      #pragma unroll
      for (int i = 0; i < 8; i++) inv[row*8 + i] = 0.f;
    }
  }

  int f0i = p * 16;
  if (active){
    union { uint16_t u[16]; uint4 q[2]; } ub;
    #pragma unroll
    for (int j = 0; j < 4; j++){
      float4 a = *(const float4*)(xe + (size_t)row*128 + f0i + j*4);
      ub.u[j*4+0]=f2bf(a.x); ub.u[j*4+1]=f2bf(a.y); ub.u[j*4+2]=f2bf(a.z); ub.u[j*4+3]=f2bf(a.w);
    }
    *(uint4*)(xebf + (size_t)row*128 + f0i)     = ub.q[0];
    *(uint4*)(xebf + (size_t)row*128 + f0i + 8) = ub.q[1];
  } else if (row < NEPAD){
    uint4 z = make_uint4(0,0,0,0);
    *(uint4*)(xebf + (size_t)row*128 + f0i)     = z;
    *(uint4*)(xebf + (size_t)row*128 + f0i + 8) = z;
  }
}

// ---- small GEMM [2048x128]@[128x128]; y=0: m1 (bias+relu); y>0: z1 pack ----
__global__ __launch_bounds__(256) void k_gemm(
    const float* __restrict__ Af, const uint16_t* __restrict__ Bm,
    const uint16_t* __restrict__ Bz, const float* __restrict__ bias,
    uint16_t* __restrict__ m1out, uint16_t* __restrict__ zpk){
  int tid = threadIdx.x;
  int lane = tid & 63, wid = tid >> 6;
  int l31 = lane & 31, g = lane >> 5;
  int by = blockIdx.y;
  bool m1path = (by == 0);
  int r = by - 1;
  const uint16_t* B = m1path ? Bm : (Bz + (size_t)r*16384);
  int arow = blockIdx.x*128 + wid*32 + l31;

  f16f acc[4];
  #pragma unroll
  for (int n = 0; n < 4; n++)
    #pragma unroll
    for (int i = 0; i < 16; i++) acc[n][i] = 0.f;

  #pragma unroll
  for (int ksI = 0; ksI < 8; ksI++){
    int k0 = ksI*16 + g*8;
    const float* ap = Af + (size_t)arow*128 + k0;
    float4 f0 = *(const float4*)ap;
    float4 f1 = *(const float4*)(ap + 4);
    union { uint16_t u[8]; bf8_t v; } ua;
    ua.u[0]=f2bf(f0.x); ua.u[1]=f2bf(f0.y); ua.u[2]=f2bf(f0.z); ua.u[3]=f2bf(f0.w);
    ua.u[4]=f2bf(f1.x); ua.u[5]=f2bf(f1.y); ua.u[6]=f2bf(f1.z); ua.u[7]=f2bf(f1.w);
    #pragma unroll
    for (int n = 0; n < 4; n++){
      bf8_t b = *(const bf8_t*)(B + (size_t)(n*32 + l31)*128 + k0);
      acc[n] = mfma32(ua.v, b, acc[n]);
    }
  }
  #pragma unroll
  for (int n = 0; n < 4; n++){
    int colg = n*32 + l31;
    float bv = m1path ? bias[colg] : 0.f;
    #pragma unroll
    for (int v = 0; v < 16; v++){
      int rowl = (v&3) + 8*(v>>2) + 4*g;
      int rg = blockIdx.x*128 + wid*32 + rowl;   // mole index j
      float val = acc[n][v];
      if (m1path){
        m1out[(size_t)rg*128 + colg] = f2bf(fmaxf(val + bv, 0.f));
      } else {
        int pos = ((rg & 1) << 2) | ((rg & 7) >> 1);
        zpk[(size_t)(r*256 + (rg>>3))*1024 + colg*8 + pos] = f2bf(val);
      }
    }
  }
}

// ---- masked conv core (shared by convA / convB): wave = 64x64, levq hoisted,
//      per-block kk rotation to spread concurrent L2 reads ----
template<bool S16, bool ROOT>
__device__ __forceinline__ void conv_core(
    const uint32_t* __restrict__ levq, const float* __restrict__ inv,
    const uint16_t* __restrict__ zpk, const uint16_t* __restrict__ aroot,
    const uint16_t* __restrict__ rt,
    uint16_t* __restrict__ p16, float* __restrict__ p32,
    int tid){
  int lane = tid & 63, wid = tid >> 6;
  int l31 = lane & 31, g = lane >> 5;
  int wm = wid >> 1, wn = wid & 1;
  int bx = blockIdx.x;
  int brow = bx*128;
  int ks = blockIdx.y;                      // 0..15
  int kc0 = ks*16;
  int rowA = brow + wm*64 + l31;
  int rowB = rowA + 32;
  int colb = wn*64;

  // hoist all levq loads, kk rotated by bx (indices static -> registers)
  uint32_t LA[8], LB[8];
  #pragma unroll
  for (int j = 0; j < 8; j++){
    int kt = kc0 + ((j + bx) & 7)*2 + g;
    LA[j] = levq[(size_t)kt*NEPAD + rowA];
    LB[j] = levq[(size_t)kt*NEPAD + rowB];
  }

  uint32_t tlo[2][5], thi[2][5];
  #pragma unroll
  for (int mt = 0; mt < 2; mt++){
    int rg = mt ? rowB : rowA;
    #pragma unroll
    for (int r = 1; r <= 5; r++){
      uint32_t bits = (uint32_t)f2bf(inv[(size_t)rg*8 + r]);
      int sh = 8*((r+1)&3);
      tlo[mt][r-1] = (bits & 0xFFu) << sh;
      thi[mt][r-1] = (bits >> 8)    << sh;
    }
  }

  f16f acc[2][2];
  #pragma unroll
  for (int a0=0;a0<2;a0++)
    #pragma unroll
    for (int b0=0;b0<2;b0++)
      #pragma unroll
      for (int i=0;i<16;i++) acc[a0][b0][i]=0.f;

  if (ROOT && ks < 8){  // root k-chunk runs under levq latency
    int k0 = ks*16 + g*8;
    bf8_t a0 = *(const bf8_t*)(aroot + (size_t)rowA*128 + k0);
    bf8_t a1 = *(const bf8_t*)(aroot + (size_t)rowB*128 + k0);
    #pragma unroll
    for (int nt = 0; nt < 2; nt++){
      bf8_t rb = *(const bf8_t*)(rt + (size_t)(colb + nt*32 + l31)*128 + k0);
      acc[0][nt] = mfma32(a0, rb, acc[0][nt]);
      acc[1][nt] = mfma32(a1, rb, acc[1][nt]);
    }
  }

  #pragma unroll
  for (int kk = 0; kk < 8; kk++){
    int kt = kc0 + ((kk + bx) & 7)*2 + g;   // same rotation as the hoist
    uint32_t sxA = LA[kk] & 0x0F0F0F0Fu, syA = (LA[kk] >> 4) & 0x0F0F0F0Fu;
    uint32_t sxB = LB[kk] & 0x0F0F0F0Fu, syB = (LB[kk] >> 4) & 0x0F0F0F0Fu;
    const uint16_t* zb = zpk + (size_t)kt*1024 + (size_t)(colb + l31)*8;
    #pragma unroll
    for (int r = 1; r <= 5; r++){
      const uint16_t* zr = zb + (size_t)(r-1)*262144;
      bf8_t bn0 = *(const bf8_t*)(zr);
      bf8_t bn1 = *(const bf8_t*)(zr + 256);
      #pragma unroll
      for (int mt = 0; mt < 2; mt++){
        uint32_t sx = mt ? sxB : sxA;
        uint32_t sy = mt ? syB : syA;
        uint32_t TL = tlo[mt][r-1], TH = thi[mt][r-1];
        uint32_t pl, ph, ql, qh;
        if (r < 3){   // table byte 2..3 -> low pool (src1)
          pl = __builtin_amdgcn_perm(0u, TL, sx);
          ph = __builtin_amdgcn_perm(0u, TH, sx);
          ql = __builtin_amdgcn_perm(0u, TL, sy);
          qh = __builtin_amdgcn_perm(0u, TH, sy);
        } else {      // table byte 4..6 -> high pool (src0)
          pl = __builtin_amdgcn_perm(TL, 0u, sx);
          ph = __builtin_amdgcn_perm(TH, 0u, sx);
          ql = __builtin_amdgcn_perm(TL, 0u, sy);
          qh = __builtin_amdgcn_perm(TH, 0u, sy);
        }
        union { uint32_t u[4]; bf8_t v; } A;
        A.u[0] = __builtin_amdgcn_perm(ph, pl, 0x05010400u);
        A.u[1] = __builtin_amdgcn_perm(ph, pl, 0x07030602u);
        A.u[2] = __builtin_amdgcn_perm(qh, ql, 0x05010400u);
        A.u[3] = __builtin_amdgcn_perm(qh, ql, 0x07030602u);
        acc[mt][0] = mfma32(A.v, bn0, acc[mt][0]);
        acc[mt][1] = mfma32(A.v, bn1, acc[mt][1]);
      }
    }
  }

  if (S16){
    uint16_t* dst = p16 + (size_t)ks*NEPAD*128;
    #pragma unroll
    for (int mt = 0; mt < 2; mt++){
      #pragma unroll
      for (int nt = 0; nt < 2; nt++){
        int colg = colb + nt*32 + l31;
        #pragma unroll
        for (int v = 0; v < 16; v++){
          int rowl = (v&3) + 8*(v>>2) + 4*g;
          dst[(size_t)(brow + wm*64 + mt*32 + rowl)*128 + colg] = f2bf(acc[mt][nt][v]);
        }
      }
    }
  } else {
    #pragma unroll
    for (int mt = 0; mt < 2; mt++){
      #pragma unroll
      for (int nt = 0; nt < 2; nt++){
        int colg = colb + nt*32 + l31;
        #pragma unroll
        for (int v = 0; v < 16; v++){
          int rowl = (v&3) + 8*(v>>2) + 4*g;
          unsafeAtomicAdd(&p32[(size_t)(brow + wm*64 + mt*32 + rowl)*128 + colg],
                          acc[mt][nt][v]);
        }
      }
    }
  }
}

// ---- convA: conv1 -> slabsA  +  fused z2 gemm blocks ----
template<bool S16>
__global__ __launch_bounds__(256, 3) void k_convA(
    const uint32_t* __restrict__ levq, const float* __restrict__ inv,
    const uint16_t* __restrict__ zpk, const uint16_t* __restrict__ aroot,
    const uint16_t* __restrict__ rt,
    const uint16_t* __restrict__ gA, const uint16_t* __restrict__ gB,
    uint16_t* __restrict__ gOut,
    uint16_t* __restrict__ p16, float* __restrict__ p32){
  int tid = threadIdx.x;
  int lane = tid & 63, wid = tid >> 6;
  int l31 = lane & 31, g = lane >> 5;

  if (blockIdx.x >= MB128){
    // fused z2 gemm: 80 blocks x 128 rows: z2[r] = pack(m1 @ W2[r])
    int b = blockIdx.y*5 + (blockIdx.x - MB128);    // 0..79
    int r = b >> 4;
    int rowb = (b & 15)*128 + wid*32;
    int arow = rowb + l31;
    const uint16_t* B = gB + (size_t)r*16384;
    f16f acc[4];
    #pragma unroll
    for (int n = 0; n < 4; n++)
      #pragma unroll
      for (int i = 0; i < 16; i++) acc[n][i] = 0.f;
    #pragma unroll
    for (int ksI = 0; ksI < 8; ksI++){
      int k0 = ksI*16 + g*8;
      bf8_t a = *(const bf8_t*)(gA + (size_t)arow*128 + k0);
      #pragma unroll
      for (int n = 0; n < 4; n++){
        bf8_t bb = *(const bf8_t*)(B + (size_t)(n*32 + l31)*128 + k0);
        acc[n] = mfma32(a, bb, acc[n]);
      }
    }
    #pragma unroll
    for (int n = 0; n < 4; n++){
      int colg = n*32 + l31;
      #pragma unroll
      for (int v = 0; v < 16; v++){
        int rowl = (v&3) + 8*(v>>2) + 4*g;
        int rg = rowb + rowl;
        int pos = ((rg & 1) << 2) | ((rg & 7) >> 1);
        gOut[(size_t)(r*256 + (rg>>3))*1024 + colg*8 + pos] = f2bf(acc[n][v]);
      }
    }
    return;
  }
  conv_core<S16, true>(levq, inv, zpk, aroot, rt, p16, p32, tid);
}

// ---- convB: conv2-masked -> slabsB  +  fused red1/root2 blocks ----
template<bool S16>
__global__ __launch_bounds__(256, 3) void k_convB(
    const uint32_t* __restrict__ levq, const float* __restrict__ inv,
    const uint16_t* __restrict__ zpk,
    const uint16_t* __restrict__ pA16, const float* __restrict__ pA32,
    const uint16_t* __restrict__ rt, const float* __restrict__ b1,
    uint16_t* __restrict__ pB16, float* __restrict__ pB32,
    float* __restrict__ rootslab){
  __shared__ uint16_t e1s[128*136];          // 34.8 KB, pitch 136 (16B-aligned rows)
  int tid = threadIdx.x;
  int lane = tid & 63, wid = tid >> 6;
  int l31 = lane & 31, g = lane >> 5;

  if (blockIdx.x >= MB128){
    // fused red1: e1 = relu(sum slabsA + b1) -> LDS; rootslab = e1 @ root2
    int rid = blockIdx.y*5 + (blockIdx.x - MB128);  // 0..79
    if (rid >= MB128) return;
    #pragma unroll
    for (int c = 0; c < 8; c++){
      int eo = c*2048 + tid*8;
      size_t base = (size_t)rid*16384 + eo;
      int col = eo & 127;
      float s[8];
      float4 bv0 = *(const float4*)(b1 + col);
      float4 bv1 = *(const float4*)(b1 + col + 4);
      s[0]=bv0.x; s[1]=bv0.y; s[2]=bv0.z; s[3]=bv0.w;
      s[4]=bv1.x; s[5]=bv1.y; s[6]=bv1.z; s[7]=bv1.w;
      if (S16){
        #pragma unroll
        for (int sl = 0; sl < KSPLIT; sl++){
          union { uint4 q; uint16_t h[8]; } u;
          u.q = *(const uint4*)(pA16 + (size_t)sl*NEPAD*128 + base);
          #pragma unroll
          for (int j = 0; j < 8; j++) s[j] += __uint_as_float(((uint32_t)u.h[j]) << 16);
        }
      } else {
        #pragma unroll
        for (int j = 0; j < 8; j += 4){
          float4 v = *(const float4*)(pA32 + base + j);
          s[j] += v.x; s[j+1] += v.y; s[j+2] += v.z; s[j+3] += v.w;
        }
      }
      union { uint16_t u[8]; uint4 q; } ub;
      #pragma unroll
      for (int j = 0; j < 8; j++) ub.u[j] = f2bf(fmaxf(s[j], 0.f));
      int row = eo >> 7;
      *(uint4*)(&e1s[row*136 + col]) = ub.q;
    }
    __syncthreads();
    f16f racc[4];
    #pragma unroll
    for (int n = 0; n < 4; n++)
      #pragma unroll
      for (int i = 0; i < 16; i++) racc[n][i] = 0.f;
    #pragma unroll
    for (int kk = 0; kk < 8; kk++){
      int k0 = kk*16 + g*8;
      bf8_t a = *(const bf8_t*)(&e1s[(wid*32 + l31)*136 + k0]);
      #pragma unroll
      for (int n = 0; n < 4; n++){
        bf8_t b = *(const bf8_t*)(rt + (size_t)(n*32 + l31)*128 + k0);
        racc[n] = mfma32(a, b, racc[n]);
      }
    }
    #pragma unroll
    for (int n = 0; n < 4; n++){
      int colg = n*32 + l31;
      #pragma unroll
      for (int v = 0; v < 16; v++){
        int rowl = (v&3) + 8*(v>>2) + 4*g;
        rootslab[(size_t)(rid*128 + wid*32 + rowl)*128 + colg] = racc[n][v];
      }
    }
    return;
  }
  conv_core<S16, false>(levq, inv, zpk, (const uint16_t*)nullptr, rt, pB16, pB32, tid);
}

// ---- red2: out = sum slabsB + rootslab + b2 (f32) ----
template<bool S16>
__global__ __launch_bounds__(256) void k_red2(
    const uint16_t* __restrict__ pB16, const float* __restrict__ pB32,
    const float* __restrict__ rootslab, const float* __restrict__ b2,
    float* __restrict__ out){
  size_t idx8 = ((size_t)blockIdx.x*256 + threadIdx.x) * 8;   // < NE*128
  if (idx8 >= (size_t)NE*128) return;
  int col = (int)(idx8 & 127);
  float s[8];
  float4 bv0 = *(const float4*)(b2 + col);
  float4 bv1 = *(const float4*)(b2 + col + 4);
  s[0]=bv0.x; s[1]=bv0.y; s[2]=bv0.z; s[3]=bv0.w;
  s[4]=bv1.x; s[5]=bv1.y; s[6]=bv1.z; s[7]=bv1.w;
  float4 r0 = *(const float4*)(rootslab + idx8);
  float4 r1 = *(const float4*)(rootslab + idx8 + 4);
  s[0]+=r0.x; s[1]+=r0.y; s[2]+=r0.z; s[3]+=r0.w;
  s[4]+=r1.x; s[5]+=r1.y; s[6]+=r1.z; s[7]+=r1.w;
  if (S16){
    #pragma unroll
    for (int sl = 0; sl < KSPLIT; sl++){
      union { uint4 q; uint16_t h[8]; } u;
      u.q = *(const uint4*)(pB16 + (size_t)sl*NEPAD*128 + idx8);
      #pragma unroll
      for (int j = 0; j < 8; j++) s[j] += __uint_as_float(((uint32_t)u.h[j]) << 16);
    }
  } else {
    #pragma unroll
    for (int j = 0; j < 8; j += 4){
      float4 v = *(const float4*)(pB32 + idx8 + j);
      s[j] += v.x; s[j+1] += v.y; s[j+2] += v.z; s[j+3] += v.w;
    }
  }
  *(float4*)(out + idx8)     = make_float4(s[0], s[1], s[2], s[3]);
  *(float4*)(out + idx8 + 4) = make_float4(s[4], s[5], s[6], s[7]);
}

extern "C" void kernel_launch(void* const* d_in, const int* in_sizes, int n_in,
                              void* d_out, int out_size, void* d_ws, size_t ws_size,
                              hipStream_t stream){
  const float* xe  = (const float*)d_in[0];
  const float* xm  = (const float*)d_in[1];
  const float* w   = (const float*)d_in[2];
  const float* W1  = (const float*)d_in[3];
  const float* r1  = (const float*)d_in[4];
  const float* b1  = (const float*)d_in[5];
  const float* W2  = (const float*)d_in[6];
  const float* r2  = (const float*)d_in[7];
  const float* b2  = (const float*)d_in[8];
  float* out = (float*)d_out;
  char* ws = (char*)d_ws;

  constexpr size_t OFF_INV  = 0;                                   // NEPAD*8*4
  constexpr size_t OFF_XEBF = OFF_INV  + (size_t)NEPAD*8*4;        // NEPAD*128*2
  constexpr size_t OFF_M1   = OFF_XEBF + (size_t)NEPAD*128*2;      // NM*128*2
  constexpr size_t OFF_Z1   = OFF_M1   + (size_t)NM*128*2;         // 5*NM*128*2
  constexpr size_t OFF_Z2   = OFF_Z1   + (size_t)5*NM*128*2;       // 5*NM*128*2
  constexpr size_t OFF_R1T  = OFF_Z2   + (size_t)5*NM*128*2;
  constexpr size_t OFF_R2T  = OFF_R1T  + 128*128*2;
  constexpr size_t OFF_W1T  = OFF_R2T  + 128*128*2;
  constexpr size_t OFF_W2T  = OFF_W1T  + (size_t)5*128*128*2;
  constexpr size_t OFF_LEVQ = OFF_W2T  + (size_t)5*128*128*2;      // 256*NEPAD*4
  constexpr size_t OFF_PA   = OFF_LEVQ + (size_t)256*NEPAD*4;
  constexpr size_t SLAB16   = (size_t)NEPAD*128*2;                 // 2.59 MB
  constexpr size_t SLABF    = (size_t)NEPAD*128*4;                 // 5.18 MB
  constexpr size_t OFF_PB   = OFF_PA   + (size_t)KSPLIT*SLAB16;
  constexpr size_t OFF_ROOT = OFF_PB   + (size_t)KSPLIT*SLAB16;
  constexpr size_t NEED_A   = OFF_ROOT + SLABF;                    // ~105 MB
  // tier B (atomic fallback): f32 slabs at PA/PA+SLABF, root after
  constexpr size_t OFF_PB_B   = OFF_PA + SLABF;
  constexpr size_t OFF_ROOT_B = OFF_PB_B + SLABF;
  constexpr size_t NEED_B     = OFF_ROOT_B + SLABF;

  float*    inv  = (float*)   (ws + OFF_INV);
  uint16_t* xebf = (uint16_t*)(ws + OFF_XEBF);
  uint16_t* m1   = (uint16_t*)(ws + OFF_M1);
  uint16_t* z1   = (uint16_t*)(ws + OFF_Z1);
  uint16_t* z2   = (uint16_t*)(ws + OFF_Z2);
  uint16_t* r1t  = (uint16_t*)(ws + OFF_R1T);
  uint16_t* r2t  = (uint16_t*)(ws + OFF_R2T);
  uint16_t* w1t  = (uint16_t*)(ws + OFF_W1T);
  uint16_t* w2t  = (uint16_t*)(ws + OFF_W2T);
  uint32_t* levq = (uint32_t*)(ws + OFF_LEVQ);

  bool tierA = (ws_size >= NEED_A);

  // D1: prep (48 blocks) + lev (316 blocks)
  hipLaunchKernelGGL(k_init, dim3(48 + NEPAD/32), dim3(256), 0, stream,
                     r1, r2, W1, W2, r1t, r2t, w1t, w2t,
                     w, xe, levq, inv, xebf);
  // D2: y=0: m1 = relu(xm@root1+b1); y=1..5: z1[y-1] = pack(xm@W1[y-1])
  hipLaunchKernelGGL(k_gemm, dim3(16,6), dim3(256), 0, stream,
                     xm, r1t, w1t, b1, m1, z1);
  if (tierA){
    uint16_t* pA   = (uint16_t*)(ws + OFF_PA);
    uint16_t* pB   = (uint16_t*)(ws + OFF_PB);
    float*    root = (float*)   (ws + OFF_ROOT);
    // D3: conv1 -> slabsA + fused z2 gemm
    hipLaunchKernelGGL((k_convA<true>), dim3(MB128 + 5, KSPLIT), dim3(256), 0, stream,
                       levq, inv, z1, xebf, r1t, m1, w2t, z2,
                       pA, (float*)nullptr);
    // D4: conv2-masked -> slabsB  ||  red1 (e1 = relu(sumA+b1); rootslab = e1@root2)
    hipLaunchKernelGGL((k_convB<true>), dim3(MB128 + 5, KSPLIT), dim3(256), 0, stream,
                       levq, inv, z2, pA, (const float*)nullptr, r2t, b1,
                       pB, (float*)nullptr, root);
    // D5: out = sumB + rootslab + b2
    hipLaunchKernelGGL((k_red2<true>), dim3((NE*128 + 2047)/2048), dim3(256), 0, stream,
                       pB, (const float*)nullptr, root, b2, out);
  } else {
    float* pA   = (float*)(ws + OFF_PA);
    float* pB   = (float*)(ws + OFF_PB_B);
    float* root = (float*)(ws + OFF_ROOT_B);
    hipMemsetAsync(pA, 0, SLABF, stream);
    hipMemsetAsync(pB, 0, SLABF, stream);
    hipLaunchKernelGGL((k_convA<false>), dim3(MB128 + 5, KSPLIT), dim3(256), 0, stream,
                       levq, inv, z1, xebf, r1t, m1, w2t, z2,
                       (uint16_t*)nullptr, pA);
    hipLaunchKernelGGL((k_convB<false>), dim3(MB128 + 5, KSPLIT), dim3(256), 0, stream,
                       levq, inv, z2, (const uint16_t*)nullptr, pA, r2t, b1,
                       (uint16_t*)nullptr, pB, root);
    hipLaunchKernelGGL((k_red2<false>), dim3((NE*128 + 2047)/2048), dim3(256), 0, stream,
                       (const uint16_t*)nullptr, pB, root, b2, out);
  }
}

// Round 15
// 110.054 us; speedup vs baseline: 1.1618x; 1.1618x over previous
//
#include <hip/hip_runtime.h>
#include <stdint.h>

// hetero_effect_graph: 2-layer RGCN over dense level-partitioned bipartite graph.
// 4 dispatches:
//  k_init  : [bx<316] lev nibbles k-major + inv + xe->bf16 ; [bx>=316] fused GEMMs:
//            m1 = relu(xm@root1+b1), z1[r] = pack(xm@W1[r])  (weights self-converted f32)
//  k_convA : conv1 partial slabsA (4-wave 128x128, wave 64x64, levq hoisted, root1
//            self-converted on ks<8) + 80 fused blocks: z2[r] = pack(m1@W2[r])
//  k_convB : conv2-masked partial slabsB + 79 fused red1 blocks:
//            e1 = relu(sum slabsA + b1) -> LDS; e1@root2 -> rootslab (f32)
//  k_red2  : out = sum slabsB + rootslab + b2 (f32)
// NOTE: relations are W[1..5]; W[0] is unused (round-14 bug was W[0..4]).

#define NE 10000
#define NM 2048
#define NEPAD 10112   // 79 * 128
#define MB128 79      // NEPAD / 128
#define KSPLIT 16

typedef short bf8_t __attribute__((ext_vector_type(8)));
typedef float f16f  __attribute__((ext_vector_type(16)));

__device__ __forceinline__ uint16_t f2bf(float f){
  uint32_t u = __float_as_uint(f);
  u += 0x7FFFu + ((u >> 16) & 1u);
  return (uint16_t)(u >> 16);
}

__device__ __forceinline__ f16f mfma32(bf8_t a, bf8_t b, f16f c){
  return __builtin_amdgcn_mfma_f32_32x32x16_bf16(a, b, c, 0, 0, 0);
}

// ---- fused: lev/inv/xebf (316 blocks) + m1/z1 GEMMs (96 blocks) ----
__global__ __launch_bounds__(256) void k_init(
    const float* __restrict__ w, const float* __restrict__ xe,
    const float* __restrict__ xm, const float* __restrict__ root1,
    const float* __restrict__ W1, const float* __restrict__ b1,
    uint32_t* __restrict__ levq, float* __restrict__ inv,
    uint16_t* __restrict__ xebf, uint16_t* __restrict__ m1,
    uint16_t* __restrict__ z1){
  int t = threadIdx.x;
  int lane = t & 63, wid = t >> 6;
  int l31 = lane & 31, g = lane >> 5;

  if (blockIdx.x >= 316){
    // ---- fused GEMM blocks: gby=0: m1 (bias+relu); gby=1..5: z1[gby-1] = xm@W1[gby] ----
    int gb = blockIdx.x - 316;         // 0..95
    int gbx = gb & 15, gby = gb >> 4;  // 16 row-blocks x 6 outputs
    bool m1path = (gby == 0);
    const float* Bsrc = m1path ? root1 : (W1 + (size_t)gby*16384);   // W1[1..5]
    int arow = gbx*128 + wid*32 + l31;

    f16f acc[4];
    #pragma unroll
    for (int n = 0; n < 4; n++)
      #pragma unroll
      for (int i = 0; i < 16; i++) acc[n][i] = 0.f;

    #pragma unroll
    for (int ksI = 0; ksI < 8; ksI++){
      int k0 = ksI*16 + g*8;
      const float* ap = xm + (size_t)arow*128 + k0;
      float4 f0 = *(const float4*)ap;
      float4 f1 = *(const float4*)(ap + 4);
      union { uint16_t u[8]; bf8_t v; } ua;
      ua.u[0]=f2bf(f0.x); ua.u[1]=f2bf(f0.y); ua.u[2]=f2bf(f0.z); ua.u[3]=f2bf(f0.w);
      ua.u[4]=f2bf(f1.x); ua.u[5]=f2bf(f1.y); ua.u[6]=f2bf(f1.z); ua.u[7]=f2bf(f1.w);
      #pragma unroll
      for (int n = 0; n < 4; n++){
        int d = n*32 + l31;
        union { uint16_t u[8]; bf8_t v; } ub;
        #pragma unroll
        for (int e = 0; e < 8; e++)
          ub.u[e] = f2bf(Bsrc[(size_t)(k0+e)*128 + d]);   // lane-coalesced
        acc[n] = mfma32(ua.v, ub.v, acc[n]);
      }
    }
    #pragma unroll
    for (int n = 0; n < 4; n++){
      int colg = n*32 + l31;
      float bv = m1path ? b1[colg] : 0.f;
      #pragma unroll
      for (int v = 0; v < 16; v++){
        int rowl = (v&3) + 8*(v>>2) + 4*g;
        int rg = gbx*128 + wid*32 + rowl;
        float val = acc[n][v];
        if (m1path){
          m1[(size_t)rg*128 + colg] = f2bf(fmaxf(val + bv, 0.f));
        } else {
          int pos = ((rg & 1) << 2) | ((rg & 7) >> 1);
          z1[(size_t)((gby-1)*256 + (rg>>3))*1024 + colg*8 + pos] = f2bf(val);
        }
      }
    }
    return;
  }

  // ---- lev part: 32 rows per block ----
  int brow = blockIdx.x * 32;
  int rloc = t >> 3, p = t & 7;          // 8 threads per row
  int row = brow + rloc;
  bool active = row < NE;
  const float* wr = w + (size_t)row * NM;
  unsigned long long cnt = 0ull;         // 5 x 12-bit packed relation counters
  __shared__ uint32_t tile[32][33];

  for (int cp = 0; cp < 8; cp++){        // 8 column-panels of 256 cols
    uint32_t packs[4];
    #pragma unroll
    for (int q = 0; q < 4; q++){
      int gck = cp*32 + p + 8*q;         // global 8-col chunk
      uint32_t L = 0;
      if (active){
        const float4* f = (const float4*)(wr + gck*8);
        float4 f0 = f[0], f1 = f[1];
        float wv[8] = {f0.x,f0.y,f0.z,f0.w, f1.x,f1.y,f1.z,f1.w};
        #pragma unroll
        for (int e = 0; e < 8; e++){
          int s = (int)ceilf(wv[e]*6.0f);          // lev+1 in 1..6
          if (s >= 2) cnt += 1ull << (12*(s-2));   // relations 1..5
          L |= (uint32_t)s << (4*e);
        }
      }
      packs[q] = L;
    }
    __syncthreads();
    #pragma unroll
    for (int q = 0; q < 4; q++) tile[p + 8*q][rloc] = packs[q];
    __syncthreads();
    int ckk = t >> 3;
    int r4  = (t & 7) * 4;
    size_t base = (size_t)(cp*32 + ckk) * NEPAD + brow + r4;
    *(uint4*)(levq + base) = make_uint4(tile[ckk][r4], tile[ckk][r4+1],
                                        tile[ckk][r4+2], tile[ckk][r4+3]);
  }

  unsigned long long c = cnt;
  c += __shfl_xor(c, 1);
  c += __shfl_xor(c, 2);
  c += __shfl_xor(c, 4);
  if (p == 0 && row < NEPAD){
    if (active){
      inv[row*8 + 0] = 0.f; inv[row*8 + 6] = 0.f; inv[row*8 + 7] = 0.f;
      #pragma unroll
      for (int r = 1; r <= 5; r++){
        uint32_t cc = (uint32_t)((c >> (12*(r-1))) & 0xFFFull);
        inv[row*8 + r] = cc ? 1.0f/(float)cc : 0.f;
      }
    } else {
      #pragma unroll
      for (int i = 0; i < 8; i++) inv[row*8 + i] = 0.f;
    }
  }

  int f0i = p * 16;
  if (active){
    union { uint16_t u[16]; uint4 q[2]; } ub;
    #pragma unroll
    for (int j = 0; j < 4; j++){
      float4 a = *(const float4*)(xe + (size_t)row*128 + f0i + j*4);
      ub.u[j*4+0]=f2bf(a.x); ub.u[j*4+1]=f2bf(a.y); ub.u[j*4+2]=f2bf(a.z); ub.u[j*4+3]=f2bf(a.w);
    }
    *(uint4*)(xebf + (size_t)row*128 + f0i)     = ub.q[0];
    *(uint4*)(xebf + (size_t)row*128 + f0i + 8) = ub.q[1];
  } else if (row < NEPAD){
    uint4 z = make_uint4(0,0,0,0);
    *(uint4*)(xebf + (size_t)row*128 + f0i)     = z;
    *(uint4*)(xebf + (size_t)row*128 + f0i + 8) = z;
  }
}

// ---- masked conv core: wave = 64x64, levq hoisted (no stagger), (256,2) ----
template<bool S16, bool ROOT>
__device__ __forceinline__ void conv_core(
    const uint32_t* __restrict__ levq, const float* __restrict__ inv,
    const uint16_t* __restrict__ zpk, const uint16_t* __restrict__ aroot,
    const float* __restrict__ rootf,
    uint16_t* __restrict__ p16, float* __restrict__ p32, int tid){
  int lane = tid & 63, wid = tid >> 6;
  int l31 = lane & 31, g = lane >> 5;
  int wm = wid >> 1, wn = wid & 1;
  int brow = blockIdx.x*128;
  int ks = blockIdx.y;                      // 0..15
  int kc0 = ks*16;
  int rowA = brow + wm*64 + l31;
  int rowB = rowA + 32;
  int colb = wn*64;

  // hoist ALL levq loads first (vmcnt retires in issue order: keep slow HBM
  // loads oldest so in-loop Z waits never block on them)
  uint32_t LA[8], LB[8];
  #pragma unroll
  for (int kk = 0; kk < 8; kk++){
    int kt = kc0 + kk*2 + g;
    LA[kk] = levq[(size_t)kt*NEPAD + rowA];
    LB[kk] = levq[(size_t)kt*NEPAD + rowB];
  }

  uint32_t tlo[2][5], thi[2][5];
  #pragma unroll
  for (int mt = 0; mt < 2; mt++){
    int rg = mt ? rowB : rowA;
    #pragma unroll
    for (int r = 1; r <= 5; r++){
      uint32_t bits = (uint32_t)f2bf(inv[(size_t)rg*8 + r]);
      int sh = 8*((r+1)&3);
      tlo[mt][r-1] = (bits & 0xFFu) << sh;
      thi[mt][r-1] = (bits >> 8)    << sh;
    }
  }

  f16f acc[2][2];
  #pragma unroll
  for (int a0=0;a0<2;a0++)
    #pragma unroll
    for (int b0=0;b0<2;b0++)
      #pragma unroll
      for (int i=0;i<16;i++) acc[a0][b0][i]=0.f;

  if (ROOT && ks < 8){  // root k-chunk (self-converted f32 B) under levq latency
    int k0 = ks*16 + g*8;
    bf8_t a0 = *(const bf8_t*)(aroot + (size_t)rowA*128 + k0);
    bf8_t a1 = *(const bf8_t*)(aroot + (size_t)rowB*128 + k0);
    #pragma unroll
    for (int nt = 0; nt < 2; nt++){
      int d = colb + nt*32 + l31;
      union { uint16_t u[8]; bf8_t v; } ub;
      #pragma unroll
      for (int e = 0; e < 8; e++)
        ub.u[e] = f2bf(rootf[(size_t)(k0+e)*128 + d]);
      acc[0][nt] = mfma32(a0, ub.v, acc[0][nt]);
      acc[1][nt] = mfma32(a1, ub.v, acc[1][nt]);
    }
  }

  #pragma unroll
  for (int kk = 0; kk < 8; kk++){
    int kt = kc0 + kk*2 + g;
    uint32_t sxA = LA[kk] & 0x0F0F0F0Fu, syA = (LA[kk] >> 4) & 0x0F0F0F0Fu;
    uint32_t sxB = LB[kk] & 0x0F0F0F0Fu, syB = (LB[kk] >> 4) & 0x0F0F0F0Fu;
    const uint16_t* zb = zpk + (size_t)kt*1024 + (size_t)(colb + l31)*8;
    #pragma unroll
    for (int r = 1; r <= 5; r++){
      const uint16_t* zr = zb + (size_t)(r-1)*262144;
      bf8_t bn0 = *(const bf8_t*)(zr);
      bf8_t bn1 = *(const bf8_t*)(zr + 256);
      #pragma unroll
      for (int mt = 0; mt < 2; mt++){
        uint32_t sx = mt ? sxB : sxA;
        uint32_t sy = mt ? syB : syA;
        uint32_t TL = tlo[mt][r-1], TH = thi[mt][r-1];
        uint32_t pl, ph, ql, qh;
        if (r < 3){   // table byte 2..3 -> low pool (src1)
          pl = __builtin_amdgcn_perm(0u, TL, sx);
          ph = __builtin_amdgcn_perm(0u, TH, sx);
          ql = __builtin_amdgcn_perm(0u, TL, sy);
          qh = __builtin_amdgcn_perm(0u, TH, sy);
        } else {      // table byte 4..6 -> high pool (src0)
          pl = __builtin_amdgcn_perm(TL, 0u, sx);
          ph = __builtin_amdgcn_perm(TH, 0u, sx);
          ql = __builtin_amdgcn_perm(TL, 0u, sy);
          qh = __builtin_amdgcn_perm(TH, 0u, sy);
        }
        union { uint32_t u[4]; bf8_t v; } A;
        A.u[0] = __builtin_amdgcn_perm(ph, pl, 0x05010400u);
        A.u[1] = __builtin_amdgcn_perm(ph, pl, 0x07030602u);
        A.u[2] = __builtin_amdgcn_perm(qh, ql, 0x05010400u);
        A.u[3] = __builtin_amdgcn_perm(qh, ql, 0x07030602u);
        acc[mt][0] = mfma32(A.v, bn0, acc[mt][0]);
        acc[mt][1] = mfma32(A.v, bn1, acc[mt][1]);
      }
    }
  }

  if (S16){
    uint16_t* dst = p16 + (size_t)ks*NEPAD*128;
    #pragma unroll
    for (int mt = 0; mt < 2; mt++){
      #pragma unroll
      for (int nt = 0; nt < 2; nt++){
        int colg = colb + nt*32 + l31;
        #pragma unroll
        for (int v = 0; v < 16; v++){
          int rowl = (v&3) + 8*(v>>2) + 4*g;
          dst[(size_t)(brow + wm*64 + mt*32 + rowl)*128 + colg] = f2bf(acc[mt][nt][v]);
        }
      }
    }
  } else {
    #pragma unroll
    for (int mt = 0; mt < 2; mt++){
      #pragma unroll
      for (int nt = 0; nt < 2; nt++){
        int colg = colb + nt*32 + l31;
        #pragma unroll
        for (int v = 0; v < 16; v++){
          int rowl = (v&3) + 8*(v>>2) + 4*g;
          unsafeAtomicAdd(&p32[(size_t)(brow + wm*64 + mt*32 + rowl)*128 + colg],
                          acc[mt][nt][v]);
        }
      }
    }
  }
}

// ---- convA: conv1 -> slabsA  +  fused z2 gemm (W2[1..5] self-converted) ----
template<bool S16>
__global__ __launch_bounds__(256, 2) void k_convA(
    const uint32_t* __restrict__ levq, const float* __restrict__ inv,
    const uint16_t* __restrict__ z1, const uint16_t* __restrict__ xebf,
    const float* __restrict__ root1,
    const uint16_t* __restrict__ m1, const float* __restrict__ W2,
    uint16_t* __restrict__ z2,
    uint16_t* __restrict__ p16, float* __restrict__ p32){
  int tid = threadIdx.x;
  int lane = tid & 63, wid = tid >> 6;
  int l31 = lane & 31, g = lane >> 5;

  if (blockIdx.x >= MB128){
    // fused z2 gemm: 80 blocks x 128 rows: z2[r] = pack(m1 @ W2[r+1])
    int fb = blockIdx.y*5 + (blockIdx.x - MB128);   // 0..79
    int r = fb >> 4;                                 // 0..4 (relation r+1)
    int rowb = (fb & 15)*128 + wid*32;
    int arow = rowb + l31;
    const float* Bsrc = W2 + (size_t)(r+1)*16384;    // W2[1..5]
    f16f acc[4];
    #pragma unroll
    for (int n = 0; n < 4; n++)
      #pragma unroll
      for (int i = 0; i < 16; i++) acc[n][i] = 0.f;
    #pragma unroll
    for (int ksI = 0; ksI < 8; ksI++){
      int k0 = ksI*16 + g*8;
      bf8_t a = *(const bf8_t*)(m1 + (size_t)arow*128 + k0);
      #pragma unroll
      for (int n = 0; n < 4; n++){
        int d = n*32 + l31;
        union { uint16_t u[8]; bf8_t v; } ub;
        #pragma unroll
        for (int e = 0; e < 8; e++)
          ub.u[e] = f2bf(Bsrc[(size_t)(k0+e)*128 + d]);
        acc[n] = mfma32(a, ub.v, acc[n]);
      }
    }
    #pragma unroll
    for (int n = 0; n < 4; n++){
      int colg = n*32 + l31;
      #pragma unroll
      for (int v = 0; v < 16; v++){
        int rowl = (v&3) + 8*(v>>2) + 4*g;
        int rg = rowb + rowl;
        int pos = ((rg & 1) << 2) | ((rg & 7) >> 1);
        z2[(size_t)(r*256 + (rg>>3))*1024 + colg*8 + pos] = f2bf(acc[n][v]);
      }
    }
    return;
  }
  conv_core<S16, true>(levq, inv, z1, xebf, root1, p16, p32, tid);
}

// ---- convB: conv2-masked -> slabsB  +  fused red1/root2 blocks ----
template<bool S16>
__global__ __launch_bounds__(256, 2) void k_convB(
    const uint32_t* __restrict__ levq, const float* __restrict__ inv,
    const uint16_t* __restrict__ z2,
    const uint16_t* __restrict__ pA16, const float* __restrict__ pA32,
    const float* __restrict__ root2, const float* __restrict__ b1,
    uint16_t* __restrict__ pB16, float* __restrict__ pB32,
    float* __restrict__ rootslab){
  __shared__ uint16_t e1s[128*136];          // 34.8 KB (pitch 136 keeps 16B rows)
  int tid = threadIdx.x;
  int lane = tid & 63, wid = tid >> 6;
  int l31 = lane & 31, g = lane >> 5;

  if (blockIdx.x >= MB128){
    // fused red1: e1 = relu(sum slabsA + b1) -> LDS; rootslab = e1 @ root2
    int rid = blockIdx.y*5 + (blockIdx.x - MB128);  // 0..79
    if (rid >= MB128) return;
    #pragma unroll
    for (int c = 0; c < 8; c++){
      int eo = c*2048 + tid*8;
      size_t base = (size_t)rid*16384 + eo;
      int col = eo & 127;
      float s[8];
      float4 bv0 = *(const float4*)(b1 + col);
      float4 bv1 = *(const float4*)(b1 + col + 4);
      s[0]=bv0.x; s[1]=bv0.y; s[2]=bv0.z; s[3]=bv0.w;
      s[4]=bv1.x; s[5]=bv1.y; s[6]=bv1.z; s[7]=bv1.w;
      if (S16){
        #pragma unroll
        for (int sl = 0; sl < KSPLIT; sl++){
          union { uint4 q; uint16_t h[8]; } u;
          u.q = *(const uint4*)(pA16 + (size_t)sl*NEPAD*128 + base);
          #pragma unroll
          for (int j = 0; j < 8; j++) s[j] += __uint_as_float(((uint32_t)u.h[j]) << 16);
        }
      } else {
        #pragma unroll
        for (int j = 0; j < 8; j += 4){
          float4 v = *(const float4*)(pA32 + base + j);
          s[j] += v.x; s[j+1] += v.y; s[j+2] += v.z; s[j+3] += v.w;
        }
      }
      union { uint16_t u[8]; uint4 q; } ub;
      #pragma unroll
      for (int j = 0; j < 8; j++) ub.u[j] = f2bf(fmaxf(s[j], 0.f));
      int row = eo >> 7;
      *(uint4*)(&e1s[row*136 + col]) = ub.q;
    }
    __syncthreads();
    f16f racc[4];
    #pragma unroll
    for (int n = 0; n < 4; n++)
      #pragma unroll
      for (int i = 0; i < 16; i++) racc[n][i] = 0.f;
    #pragma unroll
    for (int kk = 0; kk < 8; kk++){
      int k0 = kk*16 + g*8;
      bf8_t a = *(const bf8_t*)(&e1s[(wid*32 + l31)*136 + k0]);
      #pragma unroll
      for (int n = 0; n < 4; n++){
        int d = n*32 + l31;
        union { uint16_t u[8]; bf8_t v; } ub;
        #pragma unroll
        for (int e = 0; e < 8; e++)
          ub.u[e] = f2bf(root2[(size_t)(k0+e)*128 + d]);
        racc[n] = mfma32(a, ub.v, racc[n]);
      }
    }
    #pragma unroll
    for (int n = 0; n < 4; n++){
      int colg = n*32 + l31;
      #pragma unroll
      for (int v = 0; v < 16; v++){
        int rowl = (v&3) + 8*(v>>2) + 4*g;
        rootslab[(size_t)(rid*128 + wid*32 + rowl)*128 + colg] = racc[n][v];
      }
    }
    return;
  }
  conv_core<S16, false>(levq, inv, z2, (const uint16_t*)nullptr,
                        (const float*)nullptr, pB16, pB32, tid);
}

// ---- red2: out = sum slabsB + rootslab + b2 (f32) ----
template<bool S16>
__global__ __launch_bounds__(256) void k_red2(
    const uint16_t* __restrict__ pB16, const float* __restrict__ pB32,
    const float* __restrict__ rootslab, const float* __restrict__ b2,
    float* __restrict__ out){
  size_t idx8 = ((size_t)blockIdx.x*256 + threadIdx.x) * 8;   // < NE*128
  if (idx8 >= (size_t)NE*128) return;
  int col = (int)(idx8 & 127);
  float s[8];
  float4 bv0 = *(const float4*)(b2 + col);
  float4 bv1 = *(const float4*)(b2 + col + 4);
  s[0]=bv0.x; s[1]=bv0.y; s[2]=bv0.z; s[3]=bv0.w;
  s[4]=bv1.x; s[5]=bv1.y; s[6]=bv1.z; s[7]=bv1.w;
  float4 r0 = *(const float4*)(rootslab + idx8);
  float4 r1 = *(const float4*)(rootslab + idx8 + 4);
  s[0]+=r0.x; s[1]+=r0.y; s[2]+=r0.z; s[3]+=r0.w;
  s[4]+=r1.x; s[5]+=r1.y; s[6]+=r1.z; s[7]+=r1.w;
  if (S16){
    #pragma unroll
    for (int sl = 0; sl < KSPLIT; sl++){
      union { uint4 q; uint16_t h[8]; } u;
      u.q = *(const uint4*)(pB16 + (size_t)sl*NEPAD*128 + idx8);
      #pragma unroll
      for (int j = 0; j < 8; j++) s[j] += __uint_as_float(((uint32_t)u.h[j]) << 16);
    }
  } else {
    #pragma unroll
    for (int j = 0; j < 8; j += 4){
      float4 v = *(const float4*)(pB32 + idx8 + j);
      s[j] += v.x; s[j+1] += v.y; s[j+2] += v.z; s[j+3] += v.w;
    }
  }
  *(float4*)(out + idx8)     = make_float4(s[0], s[1], s[2], s[3]);
  *(float4*)(out + idx8 + 4) = make_float4(s[4], s[5], s[6], s[7]);
}

extern "C" void kernel_launch(void* const* d_in, const int* in_sizes, int n_in,
                              void* d_out, int out_size, void* d_ws, size_t ws_size,
                              hipStream_t stream){
  const float* xe  = (const float*)d_in[0];
  const float* xm  = (const float*)d_in[1];
  const float* w   = (const float*)d_in[2];
  const float* W1  = (const float*)d_in[3];
  const float* r1  = (const float*)d_in[4];
  const float* b1  = (const float*)d_in[5];
  const float* W2  = (const float*)d_in[6];
  const float* r2  = (const float*)d_in[7];
  const float* b2  = (const float*)d_in[8];
  float* out = (float*)d_out;
  char* ws = (char*)d_ws;

  constexpr size_t OFF_INV  = 0;                                   // NEPAD*8*4
  constexpr size_t OFF_XEBF = OFF_INV  + (size_t)NEPAD*8*4;        // NEPAD*128*2
  constexpr size_t OFF_M1   = OFF_XEBF + (size_t)NEPAD*128*2;      // NM*128*2
  constexpr size_t OFF_Z1   = OFF_M1   + (size_t)NM*128*2;         // 5*NM*128*2
  constexpr size_t OFF_Z2   = OFF_Z1   + (size_t)5*NM*128*2;       // 5*NM*128*2
  constexpr size_t OFF_LEVQ = OFF_Z2   + (size_t)5*NM*128*2;       // 256*NEPAD*4
  constexpr size_t OFF_PA   = OFF_LEVQ + (size_t)256*NEPAD*4;
  constexpr size_t SLAB16   = (size_t)NEPAD*128*2;                 // 2.59 MB
  constexpr size_t SLABF    = (size_t)NEPAD*128*4;                 // 5.18 MB
  constexpr size_t OFF_PB   = OFF_PA   + (size_t)KSPLIT*SLAB16;
  constexpr size_t OFF_ROOT = OFF_PB   + (size_t)KSPLIT*SLAB16;
  constexpr size_t NEED_A   = OFF_ROOT + SLABF;                    // ~107 MB
  constexpr size_t OFF_PB_B   = OFF_PA + SLABF;                    // tier-B layout
  constexpr size_t OFF_ROOT_B = OFF_PB_B + SLABF;

  float*    inv  = (float*)   (ws + OFF_INV);
  uint16_t* xebf = (uint16_t*)(ws + OFF_XEBF);
  uint16_t* m1   = (uint16_t*)(ws + OFF_M1);
  uint16_t* z1   = (uint16_t*)(ws + OFF_Z1);
  uint16_t* z2   = (uint16_t*)(ws + OFF_Z2);
  uint32_t* levq = (uint32_t*)(ws + OFF_LEVQ);

  bool tierA = (ws_size >= NEED_A);

  // D1: lev (316 blocks) + m1/z1 GEMMs (96 blocks)
  hipLaunchKernelGGL(k_init, dim3(316 + 96), dim3(256), 0, stream,
                     w, xe, xm, r1, W1, b1, levq, inv, xebf, m1, z1);
  if (tierA){
    uint16_t* pA   = (uint16_t*)(ws + OFF_PA);
    uint16_t* pB   = (uint16_t*)(ws + OFF_PB);
    float*    root = (float*)   (ws + OFF_ROOT);
    // D2: conv1 -> slabsA + fused z2 gemm
    hipLaunchKernelGGL((k_convA<true>), dim3(MB128 + 5, KSPLIT), dim3(256), 0, stream,
                       levq, inv, z1, xebf, r1, m1, W2, z2, pA, (float*)nullptr);
    // D3: conv2-masked -> slabsB || red1 (e1 = relu(sumA+b1); rootslab = e1@root2)
    hipLaunchKernelGGL((k_convB<true>), dim3(MB128 + 5, KSPLIT), dim3(256), 0, stream,
                       levq, inv, z2, pA, (const float*)nullptr, r2, b1,
                       pB, (float*)nullptr, root);
    // D4: out = sumB + rootslab + b2
    hipLaunchKernelGGL((k_red2<true>), dim3((NE*128 + 2047)/2048), dim3(256), 0, stream,
                       pB, (const float*)nullptr, root, b2, out);
  } else {
    float* pA   = (float*)(ws + OFF_PA);
    float* pB   = (float*)(ws + OFF_PB_B);
    float* root = (float*)(ws + OFF_ROOT_B);
    hipMemsetAsync(pA, 0, SLABF, stream);
    hipMemsetAsync(pB, 0, SLABF, stream);
    hipLaunchKernelGGL((k_convA<false>), dim3(MB128 + 5, KSPLIT), dim3(256), 0, stream,
                       levq, inv, z1, xebf, r1, m1, W2, z2, (uint16_t*)nullptr, pA);
    hipLaunchKernelGGL((k_convB<false>), dim3(MB128 + 5, KSPLIT), dim3(256), 0, stream,
                       levq, inv, z2, (const uint16_t*)nullptr, pA, r2, b1,
                       (uint16_t*)nullptr, pB, root);
    hipLaunchKernelGGL((k_red2<false>), dim3((NE*128 + 2047)/2048), dim3(256), 0, stream,
                       (const uint16_t*)nullptr, pB, root, b2, out);
  }
}